// Round 2
// baseline (252.611 us; speedup 1.0000x reference)
//
#include <hip/hip_runtime.h>

typedef __bf16 bf16_t;
typedef __bf16 bf16x8 __attribute__((ext_vector_type(8)));
typedef __bf16 bf16x4 __attribute__((ext_vector_type(4)));
typedef float f32x4 __attribute__((ext_vector_type(4)));

#define B_  2
#define N_  2048
#define D_  1024
#define H_  16
#define DH_ 64

#define GLL16(g, l) __builtin_amdgcn_global_load_lds( \
    (const __attribute__((address_space(1))) void*)(g), \
    (__attribute__((address_space(3))) void*)(l), 16, 0, 0)

// ---------------- RMSNorm + fused gates ----------------
// xn = x * (32/||x||) * gamma (bf16 out); gsig[row][h] = sigmoid(xn . wg[:,h] + bg[h])
// Gates use the bf16-rounded xn (same numerics as the old standalone k_gates),
// computed from registers while the row is still live — saves an 8 MB xn re-read
// and one dispatch.
__global__ __launch_bounds__(256) void k_rmsnorm_gates(const float* __restrict__ x,
    const float* __restrict__ gamma, const float* __restrict__ wg,
    const float* __restrict__ bg, bf16_t* __restrict__ xn, float* __restrict__ gsig) {
  int row = blockIdx.x;
  const float4* xr = (const float4*)(x + (size_t)row * D_);
  int tid = threadIdx.x;
  float4 v = xr[tid];
  float ss = v.x*v.x + v.y*v.y + v.z*v.z + v.w*v.w;
  #pragma unroll
  for (int off = 32; off > 0; off >>= 1) ss += __shfl_down(ss, off);
  __shared__ float red4[4];
  if ((tid & 63) == 0) red4[tid >> 6] = ss;
  __syncthreads();
  float scale = 32.0f * rsqrtf(red4[0] + red4[1] + red4[2] + red4[3]);
  float4 g = ((const float4*)gamma)[tid];
  bf16x4 o;
  o[0] = (bf16_t)(v.x * scale * g.x);
  o[1] = (bf16_t)(v.y * scale * g.y);
  o[2] = (bf16_t)(v.z * scale * g.z);
  o[3] = (bf16_t)(v.w * scale * g.w);
  *(bf16x4*)(xn + (size_t)row * D_ + tid * 4) = o;
  // ---- fused gates ----
  float xv[4] = {(float)o[0], (float)o[1], (float)o[2], (float)o[3]};
  float part[16];
  #pragma unroll
  for (int h = 0; h < 16; ++h) part[h] = 0.f;
  #pragma unroll
  for (int j = 0; j < 4; ++j) {
    const float4* wr = (const float4*)&wg[(size_t)(tid * 4 + j) * 16];
    #pragma unroll
    for (int q = 0; q < 4; ++q) {
      float4 w4 = wr[q];
      part[q * 4 + 0] += xv[j] * w4.x;
      part[q * 4 + 1] += xv[j] * w4.y;
      part[q * 4 + 2] += xv[j] * w4.z;
      part[q * 4 + 3] += xv[j] * w4.w;
    }
  }
  __shared__ float red[256][17];   // stride-17: 2-way bank aliasing only (free)
  #pragma unroll
  for (int h = 0; h < 16; ++h) red[tid][h] = part[h];
  __syncthreads();
  int h = tid & 15, grp = tid >> 4;
  float s = 0.f;
  #pragma unroll
  for (int k = 0; k < 16; ++k) s += red[grp * 16 + k][h];
  __syncthreads();
  red[grp][h] = s;
  __syncthreads();
  if (tid < 16) {
    float acc = bg[tid];
    #pragma unroll
    for (int k = 0; k < 16; ++k) acc += red[k][tid];
    gsig[(size_t)row * 16 + tid] = 1.0f / (1.0f + __expf(-acc));
  }
}

// ---------------- transpose fp32 [R][C] -> bf16 [C][R] ----------------
__global__ __launch_bounds__(256) void k_transpose_cvt(const float* __restrict__ W,
    bf16_t* __restrict__ Wt, int R, int C) {
  __shared__ float tile[32][33];
  int c0 = blockIdx.x * 32, r0 = blockIdx.y * 32;
  int tx = threadIdx.x & 31, ty = threadIdx.x >> 5;
  #pragma unroll
  for (int i = 0; i < 4; ++i) {
    int r = ty + i * 8;
    tile[r][tx] = W[(size_t)(r0 + r) * C + c0 + tx];
  }
  __syncthreads();
  #pragma unroll
  for (int i = 0; i < 4; ++i) {
    int rr = ty + i * 8;
    Wt[(size_t)(c0 + rr) * R + r0 + tx] = (bf16_t)tile[tx][rr];
  }
}

// ---------------- GEMM: C[M][N] = A[M][K] * Bt[N][K]^T, m97-style ----------------
// 128x128 tile, BK=32, global_load_lds width-16, unpadded stride-32 LDS.
template<bool OUT_BF16>
__global__ __launch_bounds__(256) void k_gemm_bt(const bf16_t* __restrict__ A,
    const bf16_t* __restrict__ Bt, void* __restrict__ Cp, int M, int N, int K) {
  constexpr int BK = 32;
  __shared__ __align__(16) bf16_t As[128 * BK];
  __shared__ __align__(16) bf16_t Bs[128 * BK];
  int tid = threadIdx.x, wave = tid >> 6, lane = tid & 63;
  int l16 = lane & 15, quad = lane >> 4;
  int bm = blockIdx.x * 128, bn = blockIdx.y * 128;
  int wm = (wave >> 1) * 64, wn = (wave & 1) * 64;
  // staging: wave w covers LDS rows [w*32, w*32+32); 2 instrs of 16 rows each
  int srow = wave * 32 + (lane >> 2);
  int scol = (lane & 3) * 8;
  const bf16_t* gA0 = &A [(size_t)(bm + srow)      * K + scol];
  const bf16_t* gA1 = &A [(size_t)(bm + srow + 16) * K + scol];
  const bf16_t* gB0 = &Bt[(size_t)(bn + srow)      * K + scol];
  const bf16_t* gB1 = &Bt[(size_t)(bn + srow + 16) * K + scol];
  bf16_t* lA0 = &As[(wave * 32)      * BK];   // wave-uniform bases
  bf16_t* lA1 = &As[(wave * 32 + 16) * BK];
  bf16_t* lB0 = &Bs[(wave * 32)      * BK];
  bf16_t* lB1 = &Bs[(wave * 32 + 16) * BK];
  f32x4 acc[4][4] = {};
  for (int k0 = 0; k0 < K; k0 += BK) {
    GLL16(gA0 + k0, lA0);
    GLL16(gA1 + k0, lA1);
    GLL16(gB0 + k0, lB0);
    GLL16(gB1 + k0, lB1);
    __syncthreads();
    bf16x8 af[4], bfr[4];
    #pragma unroll
    for (int t = 0; t < 4; ++t) {
      af[t]  = *(const bf16x8*)&As[(wm + t * 16 + l16) * BK + quad * 8];
      bfr[t] = *(const bf16x8*)&Bs[(wn + t * 16 + l16) * BK + quad * 8];
    }
    #pragma unroll
    for (int mt = 0; mt < 4; ++mt)
      #pragma unroll
      for (int nt = 0; nt < 4; ++nt)
        acc[mt][nt] = __builtin_amdgcn_mfma_f32_16x16x32_bf16(af[mt], bfr[nt], acc[mt][nt], 0, 0, 0);
    __syncthreads();
  }
  #pragma unroll
  for (int mt = 0; mt < 4; ++mt)
    #pragma unroll
    for (int nt = 0; nt < 4; ++nt)
      #pragma unroll
      for (int r = 0; r < 4; ++r) {
        int row = bm + wm + mt * 16 + quad * 4 + r;
        int col = bn + wn + nt * 16 + l16;
        float v = acc[mt][nt][r];
        if (OUT_BF16) ((bf16_t*)Cp)[(size_t)row * N + col] = (bf16_t)v;
        else          ((float*)Cp)[(size_t)row * N + col] = v;
      }
}

// ---------------- RoPE for Q,K (LDS-cached trig), Q pre-scaled by 1/8 ----------------
__global__ __launch_bounds__(256) void k_rope(const bf16_t* __restrict__ qkvb,
    const float* __restrict__ freqs, bf16_t* __restrict__ Qb, bf16_t* __restrict__ Kb) {
  int row = blockIdx.x, b = row >> 11, n = row & 2047;
  __shared__ float cs[32], sn[32];
  int tid = threadIdx.x;
  if (tid < 32) { float f = (float)n * freqs[tid]; cs[tid] = cosf(f); sn[tid] = sinf(f); }
  __syncthreads();
  const bf16_t* src = qkvb + (size_t)row * 3072;
  #pragma unroll
  for (int it = 0; it < 2; ++it) {
    int p = tid + 256 * it;            // 0..511 pairs
    int h = p >> 5, j = p & 31;
    size_t dst = ((size_t)(b * H_ + h) * N_ + n) * DH_ + 2 * j;
    float c = cs[j], s = sn[j];
    {
      float v0 = (float)src[h * 64 + 2 * j], v1 = (float)src[h * 64 + 2 * j + 1];
      union { bf16_t q[2]; unsigned u; } pk;
      pk.q[0] = (bf16_t)((v0 * c - v1 * s) * 0.125f);
      pk.q[1] = (bf16_t)((v1 * c + v0 * s) * 0.125f);
      *(unsigned*)&Qb[dst] = pk.u;
    }
    {
      float v0 = (float)src[1024 + h * 64 + 2 * j], v1 = (float)src[1024 + h * 64 + 2 * j + 1];
      union { bf16_t q[2]; unsigned u; } pk;
      pk.q[0] = (bf16_t)(v0 * c - v1 * s);
      pk.q[1] = (bf16_t)(v1 * c + v0 * s);
      *(unsigned*)&Kb[dst] = pk.u;
    }
  }
}

// ---------------- V transpose: qkvb[., 2048+h*64+d] -> Vb[bh][d][n] ----------------
__global__ __launch_bounds__(256) void k_vtrans(const bf16_t* __restrict__ qkvb,
    bf16_t* __restrict__ Vb) {
  __shared__ bf16_t Vs[64][72];
  int bh = blockIdx.x, nt = blockIdx.y;
  int b = bh >> 4, h = bh & 15;
  int n0 = nt * 64;
  int tid = threadIdx.x;
  #pragma unroll
  for (int it = 0; it < 2; ++it) {
    int chunk = tid + 256 * it;
    int nl = chunk >> 3, c = (chunk & 7) * 8;
    *(bf16x8*)&Vs[nl][c] =
        *(const bf16x8*)&qkvb[(size_t)(b * N_ + n0 + nl) * 3072 + 2048 + h * 64 + c];
  }
  __syncthreads();
  #pragma unroll
  for (int it = 0; it < 2; ++it) {
    int chunk = tid + 256 * it;
    int d = chunk >> 3, nc = (chunk & 7) * 8;
    bf16x8 o;
    #pragma unroll
    for (int jj = 0; jj < 8; ++jj) o[jj] = Vs[nc + jj][d];
    *(bf16x8*)&Vb[((size_t)bh * DH_ + d) * N_ + n0 + nc] = o;
  }
}

// ---------------- flash attention: S^T form, fixed-max softmax, 32 q/wave ----------------
// v2: double-buffered K/V LDS + async-STAGE split (issue loads at loop top, ds_write
// after compute) + single barrier per tile + setprio around MFMA clusters.
__global__ __launch_bounds__(256) void k_flash(const bf16_t* __restrict__ Qb,
    const bf16_t* __restrict__ Kb, const bf16_t* __restrict__ Vb,
    const float* __restrict__ gsig, bf16_t* __restrict__ Ao) {
  __shared__ __align__(16) bf16_t Ks[2][64 * 72];    // [buf][key][dh], stride 72
  __shared__ __align__(16) bf16_t Vt[2][64 * 72];    // [buf][dh][key], stride 72
  __shared__ __align__(16) bf16_t Ps[4][32 * 72];    // per-wave [q][key], stride 72
  int bh = blockIdx.y, b = bh >> 4, h = bh & 15;
  int tid = threadIdx.x, wave = tid >> 6, lane = tid & 63;
  int l16 = lane & 15, quad = lane >> 4;
  int qw = blockIdx.x * 128 + wave * 32;
  const bf16_t* Qh = Qb + (size_t)bh * N_ * DH_;
  const bf16_t* Kh = Kb + (size_t)bh * N_ * DH_;
  const bf16_t* Vh = Vb + (size_t)bh * DH_ * N_;     // [64][2048]
  bf16_t* Pw = Ps[wave];
  // Q fragments (B-operand): n = q row, k = d. Q pre-scaled by 1/8.
  bf16x8 qf[2][2];
  #pragma unroll
  for (int qt = 0; qt < 2; ++qt)
    #pragma unroll
    for (int hf = 0; hf < 2; ++hf)
      qf[qt][hf] = *(const bf16x8*)&Qh[(size_t)(qw + qt * 16 + l16) * DH_ + hf * 32 + quad * 8];
  f32x4 accO[2][4] = {};
  float lsum[2] = {0.f, 0.f};
  int sk = tid >> 3;                 // 0..31
  int sc = (tid & 7) * 8;
  // ---- prologue: stage tile 0 into buf 0 ----
  bf16x8 rk0 = *(const bf16x8*)&Kh[(size_t)sk * DH_ + sc];
  bf16x8 rk1 = *(const bf16x8*)&Kh[(size_t)(sk + 32) * DH_ + sc];
  bf16x8 rv0 = *(const bf16x8*)&Vh[(size_t)sk * N_ + sc];
  bf16x8 rv1 = *(const bf16x8*)&Vh[(size_t)(sk + 32) * N_ + sc];
  *(bf16x8*)&Ks[0][sk * 72 + sc]        = rk0;
  *(bf16x8*)&Ks[0][(sk + 32) * 72 + sc] = rk1;
  *(bf16x8*)&Vt[0][sk * 72 + sc]        = rv0;
  *(bf16x8*)&Vt[0][(sk + 32) * 72 + sc] = rv1;
  __syncthreads();
  for (int k0 = 0; k0 < N_; k0 += 64) {
    int cur = (k0 >> 6) & 1;
    const bf16_t* Kc = Ks[cur];
    const bf16_t* Vc = Vt[cur];
    int kn = k0 + 64;
    // ---- issue next-tile global loads NOW; HBM/L2 latency hides under compute ----
    if (kn < N_) {
      rk0 = *(const bf16x8*)&Kh[(size_t)(kn + sk) * DH_ + sc];
      rk1 = *(const bf16x8*)&Kh[(size_t)(kn + sk + 32) * DH_ + sc];
      rv0 = *(const bf16x8*)&Vh[(size_t)sk * N_ + kn + sc];
      rv1 = *(const bf16x8*)&Vh[(size_t)(sk + 32) * N_ + kn + sc];
    }
    // S^T = K . Q^T  -> C[key][q]; lane holds key=kt*16+quad*4+r, q=qt*16+l16
    f32x4 st[4][2];
    __builtin_amdgcn_s_setprio(1);
    #pragma unroll
    for (int kt = 0; kt < 4; ++kt) {
      bf16x8 kf0 = *(const bf16x8*)&Kc[(kt * 16 + l16) * 72 + quad * 8];
      bf16x8 kf1 = *(const bf16x8*)&Kc[(kt * 16 + l16) * 72 + 32 + quad * 8];
      #pragma unroll
      for (int qt = 0; qt < 2; ++qt) {
        f32x4 z = {};
        z = __builtin_amdgcn_mfma_f32_16x16x32_bf16(kf0, qf[qt][0], z, 0, 0, 0);
        z = __builtin_amdgcn_mfma_f32_16x16x32_bf16(kf1, qf[qt][1], z, 0, 0, 0);
        st[kt][qt] = z;
      }
    }
    __builtin_amdgcn_s_setprio(0);
    // fixed-max softmax: p = exp(s - 8); b64 packed store straight into A-layout
    #pragma unroll
    for (int qt = 0; qt < 2; ++qt)
      #pragma unroll
      for (int kt = 0; kt < 4; ++kt) {
        bf16x4 pk;
        #pragma unroll
        for (int r = 0; r < 4; ++r) {
          float p = __expf(st[kt][qt][r] - 8.0f);
          lsum[qt] += p;
          pk[r] = (bf16_t)p;
        }
        *(bf16x4*)&Pw[(qt * 16 + l16) * 72 + kt * 16 + quad * 4] = pk;
      }
    // P fragments (A-operand) + PV
    bf16x8 pf[2][2];
    #pragma unroll
    for (int qt = 0; qt < 2; ++qt)
      #pragma unroll
      for (int hf = 0; hf < 2; ++hf)
        pf[qt][hf] = *(const bf16x8*)&Pw[(qt * 16 + l16) * 72 + hf * 32 + quad * 8];
    __builtin_amdgcn_s_setprio(1);
    #pragma unroll
    for (int dt = 0; dt < 4; ++dt)
      #pragma unroll
      for (int hf = 0; hf < 2; ++hf) {
        bf16x8 vf = *(const bf16x8*)&Vc[(dt * 16 + l16) * 72 + hf * 32 + quad * 8];
        #pragma unroll
        for (int qt = 0; qt < 2; ++qt)
          accO[qt][dt] = __builtin_amdgcn_mfma_f32_16x16x32_bf16(pf[qt][hf], vf, accO[qt][dt], 0, 0, 0);
      }
    __builtin_amdgcn_s_setprio(0);
    // ---- write next tile into the other buffer (loads have had the whole compute
    // phase to land; the compiler's vmcnt wait here is ~free). Safe without a
    // pre-barrier: buf[cur^1] was last read in iter t-1, fenced by its end barrier.
    if (kn < N_) {
      int nb = cur ^ 1;
      *(bf16x8*)&Ks[nb][sk * 72 + sc]        = rk0;
      *(bf16x8*)&Ks[nb][(sk + 32) * 72 + sc] = rk1;
      *(bf16x8*)&Vt[nb][sk * 72 + sc]        = rv0;
      *(bf16x8*)&Vt[nb][(sk + 32) * 72 + sc] = rv1;
    }
    __syncthreads();   // single barrier per tile: fences ds_writes for next iter
  }
  // row sums: reduce over quads (lane's lsum covers keys of its quad for q=qt*16+l16)
  float lfull[2];
  #pragma unroll
  for (int qt = 0; qt < 2; ++qt) {
    float s = lsum[qt];
    s += __shfl_xor(s, 16);
    s += __shfl_xor(s, 32);
    lfull[qt] = s;
  }
  // epilogue: O in C layout (q = qt*16+quad*4+r, d = dt*16+l16)
  #pragma unroll
  for (int qt = 0; qt < 2; ++qt)
    #pragma unroll
    for (int r = 0; r < 4; ++r) {
      int qs = quad * 4 + r;
      float l_e = __shfl(lfull[qt], qs);     // lane qs holds l for q=qt*16+qs
      int q = qw + qt * 16 + qs;
      float g = gsig[((size_t)b * N_ + q) * H_ + h];
      float ginv = g / l_e;
      #pragma unroll
      for (int dt = 0; dt < 4; ++dt)
        Ao[((size_t)b * N_ + q) * (H_ * DH_) + h * DH_ + dt * 16 + l16] =
            (bf16_t)(accO[qt][dt][r] * ginv);
    }
}

extern "C" void kernel_launch(void* const* d_in, const int* in_sizes, int n_in,
                              void* d_out, int out_size, void* d_ws, size_t ws_size,
                              hipStream_t stream) {
  (void)in_sizes; (void)n_in; (void)out_size; (void)ws_size;
  const float* x      = (const float*)d_in[0];
  const float* gamma  = (const float*)d_in[1];
  const float* w_qkv  = (const float*)d_in[2];
  const float* w_gate = (const float*)d_in[3];
  const float* b_gate = (const float*)d_in[4];
  const float* w_out  = (const float*)d_in[5];
  const float* freqs  = (const float*)d_in[6];
  float* out = (float*)d_out;
  char* ws = (char*)d_ws;
  bf16_t* xn    = (bf16_t*)(ws);                          // 8 MB
  bf16_t* wqkvT = (bf16_t*)(ws + ((size_t)8  << 20));     // 6 MB
  bf16_t* woutT = (bf16_t*)(ws + ((size_t)14 << 20));     // 2 MB
  bf16_t* Qb    = (bf16_t*)(ws + ((size_t)16 << 20));     // 8 MB [bh][n][64]
  bf16_t* Kb    = (bf16_t*)(ws + ((size_t)24 << 20));     // 8 MB [bh][n][64]
  bf16_t* Vb    = (bf16_t*)(ws + ((size_t)32 << 20));     // 8 MB [bh][64][n]
  float*  gsig  = (float*) (ws + ((size_t)40 << 20));     // 256 KB
  bf16_t* attn  = (bf16_t*)(ws + ((size_t)41 << 20));     // 8 MB
  bf16_t* qkvb  = (bf16_t*)(ws + ((size_t)49 << 20));     // 24 MB

  k_transpose_cvt<<<dim3(3072 / 32, 1024 / 32), 256, 0, stream>>>(w_qkv, wqkvT, 1024, 3072);
  k_transpose_cvt<<<dim3(1024 / 32, 1024 / 32), 256, 0, stream>>>(w_out, woutT, 1024, 1024);
  k_rmsnorm_gates<<<4096, 256, 0, stream>>>(x, gamma, w_gate, b_gate, xn, gsig);
  k_gemm_bt<true><<<dim3(32, 24), 256, 0, stream>>>(xn, wqkvT, (void*)qkvb, 4096, 3072, 1024);
  k_rope<<<4096, 256, 0, stream>>>(qkvb, freqs, Qb, Kb);
  k_vtrans<<<dim3(32, 32), 256, 0, stream>>>(qkvb, Vb);
  k_flash<<<dim3(16, 32), 256, 0, stream>>>(Qb, Kb, Vb, gsig, attn);
  k_gemm_bt<false><<<dim3(32, 8), 256, 0, stream>>>(attn, woutT, (void*)out, 4096, 1024, 1024);
}

// Round 7
// 239.250 us; speedup vs baseline: 1.0558x; 1.0558x over previous
//
#include <hip/hip_runtime.h>

typedef __bf16 bf16_t;
typedef __bf16 bf16x8 __attribute__((ext_vector_type(8)));
typedef __bf16 bf16x4 __attribute__((ext_vector_type(4)));
typedef float f32x4 __attribute__((ext_vector_type(4)));

#define B_  2
#define N_  2048
#define D_  1024
#define H_  16
#define DH_ 64

// Q pre-scale: (1/sqrt(64)) * log2(e) so softmax can use raw v_exp_f32 (2^x)
#define QSCALE 0.18033688011112042f
// 8 * log2(e): folded into QK^T accumulator init => st = log2e*(s - 8)
#define NEGC  -11.541560327111707f

#if __has_builtin(__builtin_amdgcn_exp2f)
#define EXP2F(x) __builtin_amdgcn_exp2f(x)
#else
#define EXP2F(x) exp2f(x)
#endif

#define GLL16(g, l) __builtin_amdgcn_global_load_lds( \
    (const __attribute__((address_space(1))) void*)(g), \
    (__attribute__((address_space(3))) void*)(l), 16, 0, 0)

// XCD-aware chunked swizzle (T1). Requires nwg % 8 == 0 (all our grids comply).
// Consecutive hardware-dispatched ids round-robin across 8 XCDs; this remap gives
// each XCD a contiguous chunk of the flattened grid -> L2 locality for shared panels.
__device__ __forceinline__ int xcd_swizzle_id() {
  int id = blockIdx.y * gridDim.x + blockIdx.x;
  int cpx = (gridDim.x * gridDim.y) >> 3;
  return (id & 7) * cpx + (id >> 3);
}

// ---------------- RMSNorm + fused gates ----------------
__global__ __launch_bounds__(256) void k_rmsnorm_gates(const float* __restrict__ x,
    const float* __restrict__ gamma, const float* __restrict__ wg,
    const float* __restrict__ bg, bf16_t* __restrict__ xn, float* __restrict__ gsig) {
  int row = blockIdx.x;
  const float4* xr = (const float4*)(x + (size_t)row * D_);
  int tid = threadIdx.x;
  float4 v = xr[tid];
  float ss = v.x*v.x + v.y*v.y + v.z*v.z + v.w*v.w;
  #pragma unroll
  for (int off = 32; off > 0; off >>= 1) ss += __shfl_down(ss, off);
  __shared__ float red4[4];
  if ((tid & 63) == 0) red4[tid >> 6] = ss;
  __syncthreads();
  float scale = 32.0f * rsqrtf(red4[0] + red4[1] + red4[2] + red4[3]);
  float4 g = ((const float4*)gamma)[tid];
  bf16x4 o;
  o[0] = (bf16_t)(v.x * scale * g.x);
  o[1] = (bf16_t)(v.y * scale * g.y);
  o[2] = (bf16_t)(v.z * scale * g.z);
  o[3] = (bf16_t)(v.w * scale * g.w);
  *(bf16x4*)(xn + (size_t)row * D_ + tid * 4) = o;
  // ---- fused gates ----
  float xv[4] = {(float)o[0], (float)o[1], (float)o[2], (float)o[3]};
  float part[16];
  #pragma unroll
  for (int h = 0; h < 16; ++h) part[h] = 0.f;
  #pragma unroll
  for (int j = 0; j < 4; ++j) {
    const float4* wr = (const float4*)&wg[(size_t)(tid * 4 + j) * 16];
    #pragma unroll
    for (int q = 0; q < 4; ++q) {
      float4 w4 = wr[q];
      part[q * 4 + 0] += xv[j] * w4.x;
      part[q * 4 + 1] += xv[j] * w4.y;
      part[q * 4 + 2] += xv[j] * w4.z;
      part[q * 4 + 3] += xv[j] * w4.w;
    }
  }
  __shared__ float red[256][17];   // stride-17: 2-way bank aliasing only (free)
  #pragma unroll
  for (int h = 0; h < 16; ++h) red[tid][h] = part[h];
  __syncthreads();
  int h = tid & 15, grp = tid >> 4;
  float s = 0.f;
  #pragma unroll
  for (int k = 0; k < 16; ++k) s += red[grp * 16 + k][h];
  __syncthreads();
  red[grp][h] = s;
  __syncthreads();
  if (tid < 16) {
    float acc = bg[tid];
    #pragma unroll
    for (int k = 0; k < 16; ++k) acc += red[k][tid];
    gsig[(size_t)row * 16 + tid] = 1.0f / (1.0f + __expf(-acc));
  }
}

// ---------------- transpose fp32 [R][C] -> bf16 [C][R] ----------------
__global__ __launch_bounds__(256) void k_transpose_cvt(const float* __restrict__ W,
    bf16_t* __restrict__ Wt, int R, int C) {
  __shared__ float tile[32][33];
  int c0 = blockIdx.x * 32, r0 = blockIdx.y * 32;
  int tx = threadIdx.x & 31, ty = threadIdx.x >> 5;
  #pragma unroll
  for (int i = 0; i < 4; ++i) {
    int r = ty + i * 8;
    tile[r][tx] = W[(size_t)(r0 + r) * C + c0 + tx];
  }
  __syncthreads();
  #pragma unroll
  for (int i = 0; i < 4; ++i) {
    int rr = ty + i * 8;
    Wt[(size_t)(c0 + rr) * R + r0 + tx] = (bf16_t)tile[tx][rr];
  }
}

// ---------------- GEMM: C[M][N] = A[M][K] * Bt[N][K]^T, 128x128 tile ----------------
template<bool OUT_BF16>
__global__ __launch_bounds__(256) void k_gemm_bt(const bf16_t* __restrict__ A,
    const bf16_t* __restrict__ Bt, void* __restrict__ Cp, int M, int N, int K) {
  constexpr int BK = 32;
  __shared__ __align__(16) bf16_t As[128 * BK];
  __shared__ __align__(16) bf16_t Bs[128 * BK];
  int tid = threadIdx.x, wave = tid >> 6, lane = tid & 63;
  int l16 = lane & 15, quad = lane >> 4;
  int swz = xcd_swizzle_id();
  int bxi = swz % gridDim.x, byi = swz / gridDim.x;
  int bm = bxi * 128, bn = byi * 128;
  int wm = (wave >> 1) * 64, wn = (wave & 1) * 64;
  int srow = wave * 32 + (lane >> 2);
  int scol = (lane & 3) * 8;
  const bf16_t* gA0 = &A [(size_t)(bm + srow)      * K + scol];
  const bf16_t* gA1 = &A [(size_t)(bm + srow + 16) * K + scol];
  const bf16_t* gB0 = &Bt[(size_t)(bn + srow)      * K + scol];
  const bf16_t* gB1 = &Bt[(size_t)(bn + srow + 16) * K + scol];
  bf16_t* lA0 = &As[(wave * 32)      * BK];
  bf16_t* lA1 = &As[(wave * 32 + 16) * BK];
  bf16_t* lB0 = &Bs[(wave * 32)      * BK];
  bf16_t* lB1 = &Bs[(wave * 32 + 16) * BK];
  f32x4 acc[4][4] = {};
  for (int k0 = 0; k0 < K; k0 += BK) {
    GLL16(gA0 + k0, lA0);
    GLL16(gA1 + k0, lA1);
    GLL16(gB0 + k0, lB0);
    GLL16(gB1 + k0, lB1);
    __syncthreads();
    bf16x8 af[4], bfr[4];
    #pragma unroll
    for (int t = 0; t < 4; ++t) {
      af[t]  = *(const bf16x8*)&As[(wm + t * 16 + l16) * BK + quad * 8];
      bfr[t] = *(const bf16x8*)&Bs[(wn + t * 16 + l16) * BK + quad * 8];
    }
    #pragma unroll
    for (int mt = 0; mt < 4; ++mt)
      #pragma unroll
      for (int nt = 0; nt < 4; ++nt)
        acc[mt][nt] = __builtin_amdgcn_mfma_f32_16x16x32_bf16(af[mt], bfr[nt], acc[mt][nt], 0, 0, 0);
    __syncthreads();
  }
  #pragma unroll
  for (int mt = 0; mt < 4; ++mt)
    #pragma unroll
    for (int nt = 0; nt < 4; ++nt)
      #pragma unroll
      for (int r = 0; r < 4; ++r) {
        int row = bm + wm + mt * 16 + quad * 4 + r;
        int col = bn + wn + nt * 16 + l16;
        float v = acc[mt][nt][r];
        if (OUT_BF16) ((bf16_t*)Cp)[(size_t)row * N + col] = (bf16_t)v;
        else          ((float*)Cp)[(size_t)row * N + col] = v;
      }
}

// ---------------- GEMM: 128x64 tile (fp32 out) — for N=1024 out-proj ----------------
// grid (M/128, N/64) = 512 blocks -> 2 blocks/CU: TLP to hide barrier/vmcnt drains.
__global__ __launch_bounds__(256) void k_gemm_bt_n64(const bf16_t* __restrict__ A,
    const bf16_t* __restrict__ Bt, float* __restrict__ C, int M, int N, int K) {
  constexpr int BK = 32;
  __shared__ __align__(16) bf16_t As[128 * BK];
  __shared__ __align__(16) bf16_t Bs[64 * BK];
  int tid = threadIdx.x, wave = tid >> 6, lane = tid & 63;
  int l16 = lane & 15, quad = lane >> 4;
  int swz = xcd_swizzle_id();
  int bxi = swz % gridDim.x, byi = swz / gridDim.x;
  int bm = bxi * 128, bn = byi * 64;
  int wm = (wave >> 1) * 64, wn = (wave & 1) * 32;
  int srow = wave * 32 + (lane >> 2);
  int scol = (lane & 3) * 8;
  const bf16_t* gA0 = &A [(size_t)(bm + srow)      * K + scol];
  const bf16_t* gA1 = &A [(size_t)(bm + srow + 16) * K + scol];
  int srB = wave * 16 + (lane >> 2);
  const bf16_t* gB0 = &Bt[(size_t)(bn + srB) * K + scol];
  bf16_t* lA0 = &As[(wave * 32)      * BK];
  bf16_t* lA1 = &As[(wave * 32 + 16) * BK];
  bf16_t* lB0 = &Bs[(wave * 16)      * BK];
  f32x4 acc[4][2] = {};
  for (int k0 = 0; k0 < K; k0 += BK) {
    GLL16(gA0 + k0, lA0);
    GLL16(gA1 + k0, lA1);
    GLL16(gB0 + k0, lB0);
    __syncthreads();
    bf16x8 af[4], bfr[2];
    #pragma unroll
    for (int t = 0; t < 4; ++t)
      af[t]  = *(const bf16x8*)&As[(wm + t * 16 + l16) * BK + quad * 8];
    #pragma unroll
    for (int t = 0; t < 2; ++t)
      bfr[t] = *(const bf16x8*)&Bs[(wn + t * 16 + l16) * BK + quad * 8];
    #pragma unroll
    for (int mt = 0; mt < 4; ++mt)
      #pragma unroll
      for (int nt = 0; nt < 2; ++nt)
        acc[mt][nt] = __builtin_amdgcn_mfma_f32_16x16x32_bf16(af[mt], bfr[nt], acc[mt][nt], 0, 0, 0);
    __syncthreads();
  }
  #pragma unroll
  for (int mt = 0; mt < 4; ++mt)
    #pragma unroll
    for (int nt = 0; nt < 2; ++nt)
      #pragma unroll
      for (int r = 0; r < 4; ++r) {
        int row = bm + wm + mt * 16 + quad * 4 + r;
        int col = bn + wn + nt * 16 + l16;
        C[(size_t)row * N + col] = acc[mt][nt][r];
      }
}

// ---------------- RoPE for Q,K — vectorized bf16x8; Q pre-scaled by log2e/8 ----------------
__global__ __launch_bounds__(256) void k_rope(const bf16_t* __restrict__ qkvb,
    const float* __restrict__ freqs, bf16_t* __restrict__ Qb, bf16_t* __restrict__ Kb) {
  int row = blockIdx.x, b = row >> 11, n = row & 2047;
  __shared__ float cs[32], sn[32];
  int tid = threadIdx.x;
  if (tid < 32) { float f = (float)n * freqs[tid]; cs[tid] = cosf(f); sn[tid] = sinf(f); }
  __syncthreads();
  const bf16_t* src = qkvb + (size_t)row * 3072;
  int isK = tid >> 7;                 // threads 0-127: Q, 128-255: K
  int t = tid & 127;
  int h = t >> 3, j8 = (t & 7) * 8;   // 8 elements = 4 interleaved pairs
  bf16x8 v = *(const bf16x8*)&src[isK * 1024 + h * 64 + j8];
  float qs = isK ? 1.0f : QSCALE;
  bf16x8 o;
  #pragma unroll
  for (int i = 0; i < 4; ++i) {
    int jj = (j8 >> 1) + i;           // pair index 0..31
    float c = cs[jj], s = sn[jj];
    float v0 = (float)v[2 * i], v1 = (float)v[2 * i + 1];
    o[2 * i]     = (bf16_t)((v0 * c - v1 * s) * qs);
    o[2 * i + 1] = (bf16_t)((v1 * c + v0 * s) * qs);
  }
  bf16_t* dst = (isK ? Kb : Qb) + ((size_t)(b * H_ + h) * N_ + n) * DH_ + j8;
  *(bf16x8*)dst = o;
}

// ---------------- V transpose: qkvb[., 2048+h*64+d] -> Vb[bh][d][n] ----------------
__global__ __launch_bounds__(256) void k_vtrans(const bf16_t* __restrict__ qkvb,
    bf16_t* __restrict__ Vb) {
  __shared__ bf16_t Vs[64][72];
  int bh = blockIdx.x, nt = blockIdx.y;
  int b = bh >> 4, h = bh & 15;
  int n0 = nt * 64;
  int tid = threadIdx.x;
  #pragma unroll
  for (int it = 0; it < 2; ++it) {
    int chunk = tid + 256 * it;
    int nl = chunk >> 3, c = (chunk & 7) * 8;
    *(bf16x8*)&Vs[nl][c] =
        *(const bf16x8*)&qkvb[(size_t)(b * N_ + n0 + nl) * 3072 + 2048 + h * 64 + c];
  }
  __syncthreads();
  #pragma unroll
  for (int it = 0; it < 2; ++it) {
    int chunk = tid + 256 * it;
    int d = chunk >> 3, nc = (chunk & 7) * 8;
    bf16x8 o;
    #pragma unroll
    for (int jj = 0; jj < 8; ++jj) o[jj] = Vs[nc + jj][d];
    *(bf16x8*)&Vb[((size_t)bh * DH_ + d) * N_ + n0 + nc] = o;
  }
}

// ---------------- flash attention: S^T form, fixed-max softmax, 32 q/wave ----------------
// v5: + XCD swizzle (16 q-blocks sharing a head's 512 KB K/V land on one XCD's L2).
// v4: softmax 2^x (log2e folded into Q-scale, -8*log2e into C-init); row-sum via
// ones-MFMA (accL, same C-layout as accO -> no shuffle epilogue); dbuf K/V +
// async-STAGE + setprio.
__global__ __launch_bounds__(256) void k_flash(const bf16_t* __restrict__ Qb,
    const bf16_t* __restrict__ Kb, const bf16_t* __restrict__ Vb,
    const float* __restrict__ gsig, bf16_t* __restrict__ Ao) {
  __shared__ __align__(16) bf16_t Ks[2][64 * 72];    // [buf][key][dh], stride 72
  __shared__ __align__(16) bf16_t Vt[2][64 * 72];    // [buf][dh][key], stride 72
  __shared__ __align__(16) bf16_t Ps[4][32 * 72];    // per-wave [q][key], stride 72
  int swz = xcd_swizzle_id();                        // grid (16, 32): nwg=512, %8==0
  int qblk = swz & 15, bh = swz >> 4;
  int b = bh >> 4, h = bh & 15;
  int tid = threadIdx.x, wave = tid >> 6, lane = tid & 63;
  int l16 = lane & 15, quad = lane >> 4;
  int qw = qblk * 128 + wave * 32;
  const bf16_t* Qh = Qb + (size_t)bh * N_ * DH_;
  const bf16_t* Kh = Kb + (size_t)bh * N_ * DH_;
  const bf16_t* Vh = Vb + (size_t)bh * DH_ * N_;     // [64][2048]
  bf16_t* Pw = Ps[wave];
  bf16x8 qf[2][2];
  #pragma unroll
  for (int qt = 0; qt < 2; ++qt)
    #pragma unroll
    for (int hf = 0; hf < 2; ++hf)
      qf[qt][hf] = *(const bf16x8*)&Qh[(size_t)(qw + qt * 16 + l16) * DH_ + hf * 32 + quad * 8];
  bf16x8 onesf;
  #pragma unroll
  for (int i = 0; i < 8; ++i) onesf[i] = (bf16_t)1.0f;
  f32x4 accO[2][4] = {};
  f32x4 accL[2] = {};                // row-sum via ones-MFMA; same layout as accO
  int sk = tid >> 3;                 // 0..31
  int sc = (tid & 7) * 8;
  // ---- prologue: stage tile 0 into buf 0 ----
  bf16x8 rk0 = *(const bf16x8*)&Kh[(size_t)sk * DH_ + sc];
  bf16x8 rk1 = *(const bf16x8*)&Kh[(size_t)(sk + 32) * DH_ + sc];
  bf16x8 rv0 = *(const bf16x8*)&Vh[(size_t)sk * N_ + sc];
  bf16x8 rv1 = *(const bf16x8*)&Vh[(size_t)(sk + 32) * N_ + sc];
  *(bf16x8*)&Ks[0][sk * 72 + sc]        = rk0;
  *(bf16x8*)&Ks[0][(sk + 32) * 72 + sc] = rk1;
  *(bf16x8*)&Vt[0][sk * 72 + sc]        = rv0;
  *(bf16x8*)&Vt[0][(sk + 32) * 72 + sc] = rv1;
  __syncthreads();
  const f32x4 zinit = {NEGC, NEGC, NEGC, NEGC};
  for (int k0 = 0; k0 < N_; k0 += 64) {
    int cur = (k0 >> 6) & 1;
    const bf16_t* Kc = Ks[cur];
    const bf16_t* Vc = Vt[cur];
    int kn = k0 + 64;
    if (kn < N_) {
      rk0 = *(const bf16x8*)&Kh[(size_t)(kn + sk) * DH_ + sc];
      rk1 = *(const bf16x8*)&Kh[(size_t)(kn + sk + 32) * DH_ + sc];
      rv0 = *(const bf16x8*)&Vh[(size_t)sk * N_ + kn + sc];
      rv1 = *(const bf16x8*)&Vh[(size_t)(sk + 32) * N_ + kn + sc];
    }
    // S^T = K . Q^T -> C[key][q]; C-init = -8*log2e so st = log2e*(s-8)
    f32x4 st[4][2];
    __builtin_amdgcn_s_setprio(1);
    #pragma unroll
    for (int kt = 0; kt < 4; ++kt) {
      bf16x8 kf0 = *(const bf16x8*)&Kc[(kt * 16 + l16) * 72 + quad * 8];
      bf16x8 kf1 = *(const bf16x8*)&Kc[(kt * 16 + l16) * 72 + 32 + quad * 8];
      #pragma unroll
      for (int qt = 0; qt < 2; ++qt) {
        f32x4 z = zinit;
        z = __builtin_amdgcn_mfma_f32_16x16x32_bf16(kf0, qf[qt][0], z, 0, 0, 0);
        z = __builtin_amdgcn_mfma_f32_16x16x32_bf16(kf1, qf[qt][1], z, 0, 0, 0);
        st[kt][qt] = z;
      }
    }
    __builtin_amdgcn_s_setprio(0);
    // softmax: p = 2^st (bare v_exp_f32)
    #pragma unroll
    for (int qt = 0; qt < 2; ++qt)
      #pragma unroll
      for (int kt = 0; kt < 4; ++kt) {
        bf16x4 pk;
        #pragma unroll
        for (int r = 0; r < 4; ++r)
          pk[r] = (bf16_t)EXP2F(st[kt][qt][r]);
        *(bf16x4*)&Pw[(qt * 16 + l16) * 72 + kt * 16 + quad * 4] = pk;
      }
    // P fragments (A-operand) + PV; row-sum via ones-MFMA on the matrix pipe
    bf16x8 pf[2][2];
    #pragma unroll
    for (int qt = 0; qt < 2; ++qt)
      #pragma unroll
      for (int hf = 0; hf < 2; ++hf)
        pf[qt][hf] = *(const bf16x8*)&Pw[(qt * 16 + l16) * 72 + hf * 32 + quad * 8];
    __builtin_amdgcn_s_setprio(1);
    #pragma unroll
    for (int qt = 0; qt < 2; ++qt) {
      accL[qt] = __builtin_amdgcn_mfma_f32_16x16x32_bf16(pf[qt][0], onesf, accL[qt], 0, 0, 0);
      accL[qt] = __builtin_amdgcn_mfma_f32_16x16x32_bf16(pf[qt][1], onesf, accL[qt], 0, 0, 0);
    }
    #pragma unroll
    for (int dt = 0; dt < 4; ++dt)
      #pragma unroll
      for (int hf = 0; hf < 2; ++hf) {
        bf16x8 vf = *(const bf16x8*)&Vc[(dt * 16 + l16) * 72 + hf * 32 + quad * 8];
        #pragma unroll
        for (int qt = 0; qt < 2; ++qt)
          accO[qt][dt] = __builtin_amdgcn_mfma_f32_16x16x32_bf16(pf[qt][hf], vf, accO[qt][dt], 0, 0, 0);
      }
    __builtin_amdgcn_s_setprio(0);
    if (kn < N_) {
      int nb = cur ^ 1;
      *(bf16x8*)&Ks[nb][sk * 72 + sc]        = rk0;
      *(bf16x8*)&Ks[nb][(sk + 32) * 72 + sc] = rk1;
      *(bf16x8*)&Vt[nb][sk * 72 + sc]        = rv0;
      *(bf16x8*)&Vt[nb][(sk + 32) * 72 + sc] = rv1;
    }
    __syncthreads();
  }
  // epilogue: O and L are both in C layout (q = qt*16+quad*4+r, d = dt*16+l16)
  #pragma unroll
  for (int qt = 0; qt < 2; ++qt)
    #pragma unroll
    for (int r = 0; r < 4; ++r) {
      int q = qw + qt * 16 + quad * 4 + r;
      float g = gsig[((size_t)b * N_ + q) * H_ + h];
      float ginv = g / accL[qt][r];
      #pragma unroll
      for (int dt = 0; dt < 4; ++dt)
        Ao[((size_t)b * N_ + q) * (H_ * DH_) + h * DH_ + dt * 16 + l16] =
            (bf16_t)(accO[qt][dt][r] * ginv);
    }
}

extern "C" void kernel_launch(void* const* d_in, const int* in_sizes, int n_in,
                              void* d_out, int out_size, void* d_ws, size_t ws_size,
                              hipStream_t stream) {
  (void)in_sizes; (void)n_in; (void)out_size; (void)ws_size;
  const float* x      = (const float*)d_in[0];
  const float* gamma  = (const float*)d_in[1];
  const float* w_qkv  = (const float*)d_in[2];
  const float* w_gate = (const float*)d_in[3];
  const float* b_gate = (const float*)d_in[4];
  const float* w_out  = (const float*)d_in[5];
  const float* freqs  = (const float*)d_in[6];
  float* out = (float*)d_out;
  char* ws = (char*)d_ws;
  bf16_t* xn    = (bf16_t*)(ws);                          // 8 MB
  bf16_t* wqkvT = (bf16_t*)(ws + ((size_t)8  << 20));     // 6 MB
  bf16_t* woutT = (bf16_t*)(ws + ((size_t)14 << 20));     // 2 MB
  bf16_t* Qb    = (bf16_t*)(ws + ((size_t)16 << 20));     // 8 MB [bh][n][64]
  bf16_t* Kb    = (bf16_t*)(ws + ((size_t)24 << 20));     // 8 MB [bh][n][64]
  bf16_t* Vb    = (bf16_t*)(ws + ((size_t)32 << 20));     // 8 MB [bh][64][n]
  float*  gsig  = (float*) (ws + ((size_t)40 << 20));     // 256 KB
  bf16_t* attn  = (bf16_t*)(ws + ((size_t)41 << 20));     // 8 MB
  bf16_t* qkvb  = (bf16_t*)(ws + ((size_t)49 << 20));     // 24 MB

  k_transpose_cvt<<<dim3(3072 / 32, 1024 / 32), 256, 0, stream>>>(w_qkv, wqkvT, 1024, 3072);
  k_transpose_cvt<<<dim3(1024 / 32, 1024 / 32), 256, 0, stream>>>(w_out, woutT, 1024, 1024);
  k_rmsnorm_gates<<<4096, 256, 0, stream>>>(x, gamma, w_gate, b_gate, xn, gsig);
  k_gemm_bt<true><<<dim3(32, 24), 256, 0, stream>>>(xn, wqkvT, (void*)qkvb, 4096, 3072, 1024);
  k_rope<<<4096, 256, 0, stream>>>(qkvb, freqs, Qb, Kb);
  k_vtrans<<<dim3(32, 32), 256, 0, stream>>>(qkvb, Vb);
  k_flash<<<dim3(16, 32), 256, 0, stream>>>(Qb, Kb, Vb, gsig, attn);
  k_gemm_bt_n64<<<dim3(32, 16), 256, 0, stream>>>(attn, woutT, out, 4096, 1024, 1024);
}